// Round 1
// baseline (493.293 us; speedup 1.0000x reference)
//
#include <hip/hip_runtime.h>

// Problem constants
#define B_  4
#define S_  2048
#define D_  1024
#define H_  16
#define HD_ 64
#define M_  (B_*S_)   // 8192 rows total

typedef _Float16 f16;
typedef f16  f16x8 __attribute__((ext_vector_type(8)));
typedef f16  f16x4 __attribute__((ext_vector_type(4)));
typedef float f32x4 __attribute__((ext_vector_type(4)));

// ---------------------------------------------------------------- converts
__global__ __launch_bounds__(256) void cvt_kernel(const float* __restrict__ in,
                                                  f16* __restrict__ out, int n4) {
    int i = blockIdx.x * 256 + threadIdx.x;
    if (i < n4) {
        f32x4 v = *reinterpret_cast<const f32x4*>(in + (size_t)i * 4);
        *reinterpret_cast<f16x4*>(out + (size_t)i * 4) = __builtin_convertvector(v, f16x4);
    }
}

// W[K=1024][N=1024] f32 -> WT[N][K] f16
__global__ __launch_bounds__(256) void transpose_cvt_kernel(const float* __restrict__ W,
                                                            f16* __restrict__ WT) {
    __shared__ float tile[32][33];
    const int n0 = blockIdx.x * 32, k0 = blockIdx.y * 32;
    const int tx = threadIdx.x, ty = threadIdx.y; // (32,8)
#pragma unroll
    for (int j = 0; j < 4; ++j)
        tile[ty + 8 * j][tx] = W[(size_t)(k0 + ty + 8 * j) * D_ + n0 + tx];
    __syncthreads();
#pragma unroll
    for (int j = 0; j < 4; ++j)
        WT[(size_t)(n0 + ty + 8 * j) * D_ + k0 + tx] = (f16)tile[tx][ty + 8 * j];
}

// ---------------------------------------------------------------- GEMM  C = A @ Bt^T + bias
// A[M][1024] f16 row-major, Bt[N=1024][1024] f16 row-major (i.e. B transposed)
// 128x128 tile, BK=32, 256 threads = 4 waves, each wave 64x64 via 4x4 16x16x32 MFMAs.
template <typename OutT>
__global__ __launch_bounds__(256) void gemm_bt(const f16* __restrict__ A,
                                               const f16* __restrict__ Bt,
                                               const float* __restrict__ bias,
                                               OutT* __restrict__ C) {
    constexpr int K = D_;
    __shared__ __align__(16) f16 Al[128][40]; // +8 pad: 80B row stride -> conflict-free-ish reads
    __shared__ __align__(16) f16 Bl[128][40];
    const int m0 = blockIdx.y * 128, n0 = blockIdx.x * 128;
    const int tid = threadIdx.x;
    const int w = tid >> 6, l = tid & 63, lr = l & 15, lg = l >> 4;
    const int wr = w >> 1, wc = w & 1;
    f32x4 acc[4][4] = {};
    for (int kk = 0; kk < K; kk += 32) {
        __syncthreads();
#pragma unroll
        for (int i = 0; i < 2; ++i) { // 512 chunks of 16B per operand tile
            int c = tid + i * 256;
            int row = c >> 2, off = (c & 3) * 8;
            *reinterpret_cast<f16x8*>(&Al[row][off]) =
                *reinterpret_cast<const f16x8*>(A + (size_t)(m0 + row) * K + kk + off);
            *reinterpret_cast<f16x8*>(&Bl[row][off]) =
                *reinterpret_cast<const f16x8*>(Bt + (size_t)(n0 + row) * K + kk + off);
        }
        __syncthreads();
        f16x8 a[4], b[4];
#pragma unroll
        for (int m = 0; m < 4; ++m)
            a[m] = *reinterpret_cast<const f16x8*>(&Al[wr * 64 + m * 16 + lr][lg * 8]);
#pragma unroll
        for (int n = 0; n < 4; ++n)
            b[n] = *reinterpret_cast<const f16x8*>(&Bl[wc * 64 + n * 16 + lr][lg * 8]);
#pragma unroll
        for (int m = 0; m < 4; ++m)
#pragma unroll
            for (int n = 0; n < 4; ++n)
                acc[m][n] = __builtin_amdgcn_mfma_f32_16x16x32_f16(a[m], b[n], acc[m][n], 0, 0, 0);
    }
#pragma unroll
    for (int n = 0; n < 4; ++n) {
        const int col = n0 + wc * 64 + n * 16 + lr;
        const float bv = bias[col];
#pragma unroll
        for (int m = 0; m < 4; ++m) {
            const int row = m0 + wr * 64 + m * 16 + lg * 4;
#pragma unroll
            for (int r = 0; r < 4; ++r)
                C[(size_t)(row + r) * D_ + col] = (OutT)(acc[m][n][r] + bv);
        }
    }
}

// ---------------------------------------------------------------- causal flash attention
// grid (S/64, H, B), 256 threads = 4 waves; wave handles 16 q-rows, tiles of 64 keys.
__global__ __launch_bounds__(256) void attn_kernel(const f16* __restrict__ Q,
                                                   const f16* __restrict__ Kg,
                                                   const f16* __restrict__ V,
                                                   f16* __restrict__ Z) {
    __shared__ __align__(16) f16 Vt[64][72];      // V tile transposed: Vt[d][t]
    __shared__ __align__(16) f16 Pl[4][16][72];   // per-wave P tile (16q x 64t), padded
    const int q0 = blockIdx.x * 64;
    const int h = blockIdx.y, b = blockIdx.z;
    const int tid = threadIdx.x, w = tid >> 6, l = tid & 63, lr = l & 15, lg = l >> 4;
    const size_t base = ((size_t)b * S_) * D_ + h * HD_;

    f16x8 qf[2];
    {
        const int qrow = q0 + w * 16 + lr;
#pragma unroll
        for (int kd = 0; kd < 2; ++kd)
            qf[kd] = *reinterpret_cast<const f16x8*>(Q + base + (size_t)qrow * D_ + kd * 32 + lg * 8);
    }
    f32x4 zacc[4] = {};
    float mprev[4], lsum[4];
#pragma unroll
    for (int r = 0; r < 4; ++r) { mprev[r] = -__builtin_inff(); lsum[r] = 0.f; }

    const int ntiles = blockIdx.x + 1; // causal: only tiles with t0 <= q0
    for (int it = 0; it < ntiles; ++it) {
        const int t0 = it * 64;
        __syncthreads(); // protect Vt from previous iteration's readers
#pragma unroll
        for (int i = 0; i < 16; ++i) { // stage V tile transposed
            int e = tid + i * 256;
            int t = e >> 6, d = e & 63;
            Vt[d][t] = V[base + (size_t)(t0 + t) * D_ + d];
        }
        __syncthreads();
        // S = Q K^T
        f32x4 sf[4] = {};
#pragma unroll
        for (int kd = 0; kd < 2; ++kd)
#pragma unroll
            for (int n = 0; n < 4; ++n) {
                f16x8 kf = *reinterpret_cast<const f16x8*>(
                    Kg + base + (size_t)(t0 + n * 16 + lr) * D_ + kd * 32 + lg * 8);
                sf[n] = __builtin_amdgcn_mfma_f32_16x16x32_f16(qf[kd], kf, sf[n], 0, 0, 0);
            }
        const bool diag = (it == ntiles - 1);
#pragma unroll
        for (int n = 0; n < 4; ++n)
#pragma unroll
            for (int r = 0; r < 4; ++r) {
                float v = sf[n][r] * 0.125f; // 1/sqrt(64)
                if (diag && (t0 + n * 16 + lr > q0 + w * 16 + lg * 4 + r)) v = -__builtin_inff();
                sf[n][r] = v;
            }
        // online softmax (rows live in (lg, r); reduce over lanes%16 and n)
        float mnew[4], alpha[4];
#pragma unroll
        for (int r = 0; r < 4; ++r) {
            float v = fmaxf(fmaxf(sf[0][r], sf[1][r]), fmaxf(sf[2][r], sf[3][r]));
            v = fmaxf(v, __shfl_xor(v, 1));
            v = fmaxf(v, __shfl_xor(v, 2));
            v = fmaxf(v, __shfl_xor(v, 4));
            v = fmaxf(v, __shfl_xor(v, 8));
            mnew[r] = fmaxf(mprev[r], v);
            alpha[r] = __expf(mprev[r] - mnew[r]);
            mprev[r] = mnew[r];
        }
#pragma unroll
        for (int r = 0; r < 4; ++r) {
            float s = 0.f;
#pragma unroll
            for (int n = 0; n < 4; ++n) {
                float p = __expf(sf[n][r] - mnew[r]);
                sf[n][r] = p;
                s += p;
            }
            s += __shfl_xor(s, 1);
            s += __shfl_xor(s, 2);
            s += __shfl_xor(s, 4);
            s += __shfl_xor(s, 8);
            lsum[r] = lsum[r] * alpha[r] + s;
#pragma unroll
            for (int n = 0; n < 4; ++n) zacc[n][r] *= alpha[r];
        }
        // P -> per-wave LDS (layout convert D-frag -> A-frag); wave-internal, no barrier needed
#pragma unroll
        for (int n = 0; n < 4; ++n)
#pragma unroll
            for (int r = 0; r < 4; ++r)
                Pl[w][lg * 4 + r][n * 16 + lr] = (f16)sf[n][r];
        // Z += P V
#pragma unroll
        for (int kt = 0; kt < 2; ++kt) {
            f16x8 pa = *reinterpret_cast<const f16x8*>(&Pl[w][lr][kt * 32 + lg * 8]);
#pragma unroll
            for (int n = 0; n < 4; ++n) {
                f16x8 vf = *reinterpret_cast<const f16x8*>(&Vt[n * 16 + lr][kt * 32 + lg * 8]);
                zacc[n] = __builtin_amdgcn_mfma_f32_16x16x32_f16(pa, vf, zacc[n], 0, 0, 0);
            }
        }
    }
#pragma unroll
    for (int n = 0; n < 4; ++n)
#pragma unroll
        for (int r = 0; r < 4; ++r)
            Z[base + (size_t)(q0 + w * 16 + lg * 4 + r) * D_ + n * 16 + lr] =
                (f16)(zacc[n][r] / lsum[r]);
}

// ---------------------------------------------------------------- launcher
extern "C" void kernel_launch(void* const* d_in, const int* in_sizes, int n_in,
                              void* d_out, int out_size, void* d_ws, size_t ws_size,
                              hipStream_t stream) {
    const float* data    = (const float*)d_in[0];
    const float* context = (const float*)d_in[1];
    const float* Wq = (const float*)d_in[2];
    const float* bq = (const float*)d_in[3];
    const float* Wk = (const float*)d_in[4];
    const float* bk = (const float*)d_in[5];
    const float* Wv = (const float*)d_in[6];
    const float* bv = (const float*)d_in[7];
    const float* Wo = (const float*)d_in[8];
    const float* bo = (const float*)d_in[9];

    const size_t MD = (size_t)M_ * D_; // 8,388,608 elements
    const size_t DD = (size_t)D_ * D_; // 1,048,576
    f16* dataB = (f16*)d_ws;
    f16* ctxB  = dataB + MD;
    f16* WqT   = ctxB + MD;
    f16* WkT   = WqT + DD;
    f16* WvT   = WkT + DD;
    f16* WoT   = WvT + DD;
    f16* Qb    = WoT + DD;
    f16* Kb    = Qb + MD;
    f16* Vb    = Kb + MD;
    f16* Zb    = Vb + MD; // total 104 MB of ws

    const int n4 = (int)(MD / 4);
    cvt_kernel<<<n4 / 256, 256, 0, stream>>>(data, dataB, n4);
    cvt_kernel<<<n4 / 256, 256, 0, stream>>>(context, ctxB, n4);
    dim3 tb(32, 8), tg(32, 32);
    transpose_cvt_kernel<<<tg, tb, 0, stream>>>(Wq, WqT);
    transpose_cvt_kernel<<<tg, tb, 0, stream>>>(Wk, WkT);
    transpose_cvt_kernel<<<tg, tb, 0, stream>>>(Wv, WvT);
    transpose_cvt_kernel<<<tg, tb, 0, stream>>>(Wo, WoT);

    dim3 gg(D_ / 128, M_ / 128); // (8, 64)
    gemm_bt<f16><<<gg, 256, 0, stream>>>(dataB, WqT, bq, Qb);
    gemm_bt<f16><<<gg, 256, 0, stream>>>(ctxB,  WkT, bk, Kb);
    gemm_bt<f16><<<gg, 256, 0, stream>>>(ctxB,  WvT, bv, Vb);

    attn_kernel<<<dim3(S_ / 64, H_, B_), 256, 0, stream>>>(Qb, Kb, Vb, Zb);

    gemm_bt<float><<<gg, 256, 0, stream>>>(Zb, WoT, bo, (float*)d_out);
}

// Round 2
// 391.654 us; speedup vs baseline: 1.2595x; 1.2595x over previous
//
#include <hip/hip_runtime.h>

// Problem constants
#define B_  4
#define S_  2048
#define D_  1024
#define H_  16
#define HD_ 64
#define M_  (B_*S_)   // 8192 rows total

typedef _Float16 f16;
typedef f16  f16x8 __attribute__((ext_vector_type(8)));
typedef f16  f16x4 __attribute__((ext_vector_type(4)));
typedef float f32x4 __attribute__((ext_vector_type(4)));

// ---------------------------------------------------------------- converts
__global__ __launch_bounds__(256) void cvt_kernel(const float* __restrict__ in,
                                                  f16* __restrict__ out, int n4) {
    int i = blockIdx.x * 256 + threadIdx.x;
    if (i < n4) {
        f32x4 v = *reinterpret_cast<const f32x4*>(in + (size_t)i * 4);
        *reinterpret_cast<f16x4*>(out + (size_t)i * 4) = __builtin_convertvector(v, f16x4);
    }
}

// W[K=1024][N=1024] f32 -> WT[N][K] f16
__global__ __launch_bounds__(256) void transpose_cvt_kernel(const float* __restrict__ W,
                                                            f16* __restrict__ WT) {
    __shared__ float tile[32][33];
    const int n0 = blockIdx.x * 32, k0 = blockIdx.y * 32;
    const int tx = threadIdx.x, ty = threadIdx.y; // (32,8)
#pragma unroll
    for (int j = 0; j < 4; ++j)
        tile[ty + 8 * j][tx] = W[(size_t)(k0 + ty + 8 * j) * D_ + n0 + tx];
    __syncthreads();
#pragma unroll
    for (int j = 0; j < 4; ++j)
        WT[(size_t)(n0 + ty + 8 * j) * D_ + k0 + tx] = (f16)tile[tx][ty + 8 * j];
}

// ---------------------------------------------------------------- GEMM  C = A @ Bt^T + bias
// MODE 0: OutT=f16 row-major [M][D].  MODE 1: float row-major (final output).
// MODE 2: f16, output written transposed per-head: VT[B][H][HD][S] (for attention V).
template <int MODE, typename OutT>
__global__ __launch_bounds__(256) void gemm_bt(const f16* __restrict__ A,
                                               const f16* __restrict__ Bt,
                                               const float* __restrict__ bias,
                                               OutT* __restrict__ C) {
    constexpr int K = D_;
    __shared__ __align__(16) f16 Al[128][40];
    __shared__ __align__(16) f16 Bl[128][40];
    const int m0 = blockIdx.y * 128, n0 = blockIdx.x * 128;
    const int tid = threadIdx.x;
    const int w = tid >> 6, l = tid & 63, lr = l & 15, lg = l >> 4;
    const int wr = w >> 1, wc = w & 1;
    f32x4 acc[4][4] = {};
    for (int kk = 0; kk < K; kk += 32) {
        __syncthreads();
#pragma unroll
        for (int i = 0; i < 2; ++i) {
            int c = tid + i * 256;
            int row = c >> 2, off = (c & 3) * 8;
            *reinterpret_cast<f16x8*>(&Al[row][off]) =
                *reinterpret_cast<const f16x8*>(A + (size_t)(m0 + row) * K + kk + off);
            *reinterpret_cast<f16x8*>(&Bl[row][off]) =
                *reinterpret_cast<const f16x8*>(Bt + (size_t)(n0 + row) * K + kk + off);
        }
        __syncthreads();
        f16x8 a[4], b[4];
#pragma unroll
        for (int m = 0; m < 4; ++m)
            a[m] = *reinterpret_cast<const f16x8*>(&Al[wr * 64 + m * 16 + lr][lg * 8]);
#pragma unroll
        for (int n = 0; n < 4; ++n)
            b[n] = *reinterpret_cast<const f16x8*>(&Bl[wc * 64 + n * 16 + lr][lg * 8]);
#pragma unroll
        for (int m = 0; m < 4; ++m)
#pragma unroll
            for (int n = 0; n < 4; ++n)
                acc[m][n] = __builtin_amdgcn_mfma_f32_16x16x32_f16(a[m], b[n], acc[m][n], 0, 0, 0);
    }
#pragma unroll
    for (int n = 0; n < 4; ++n) {
        const int col = n0 + wc * 64 + n * 16 + lr;
        const float bv = bias[col];
#pragma unroll
        for (int m = 0; m < 4; ++m) {
            const int row = m0 + wr * 64 + m * 16 + lg * 4;
            if (MODE == 2) {
                // VT[((b*1024)+col)*2048 + s], 4 consecutive s -> f16x4 store
                const int bb = row >> 11, s0 = row & 2047;
                f16x4 v;
#pragma unroll
                for (int r = 0; r < 4; ++r) v[r] = (f16)(acc[m][n][r] + bv);
                *reinterpret_cast<f16x4*>((f16*)C + ((size_t)(bb * D_ + col)) * S_ + s0) = v;
            } else {
#pragma unroll
                for (int r = 0; r < 4; ++r)
                    C[(size_t)(row + r) * D_ + col] = (OutT)(acc[m][n][r] + bv);
            }
        }
    }
}

// ---------------------------------------------------------------- causal flash attention
// grid (S/128, H, B), 256 threads = 4 waves, NO barriers.
// Wave w owns 32 q-rows (2 m-frags of 16). KV tile = 64 keys.
// K read direct from global [B,S,D]; V read direct from VT[B][H][HD][S].
__global__ __launch_bounds__(256) void attn_kernel(const f16* __restrict__ Q,
                                                   const f16* __restrict__ Kg,
                                                   const f16* __restrict__ Vt,
                                                   f16* __restrict__ Z) {
    __shared__ __align__(16) f16 Pl[4][32][72]; // per-wave P (32q x 64k), padded
    const int q0 = blockIdx.x * 128;
    const int h = blockIdx.y, b = blockIdx.z;
    const int tid = threadIdx.x, w = tid >> 6, l = tid & 63, lr = l & 15, lg = l >> 4;
    const size_t base   = ((size_t)b * S_) * D_ + h * HD_;
    const size_t vtbase = ((size_t)(b * D_ + h * HD_)) * S_;
    const int wq0 = q0 + w * 32;

    f16x8 qf[2][2];
#pragma unroll
    for (int mf = 0; mf < 2; ++mf)
#pragma unroll
        for (int kd = 0; kd < 2; ++kd)
            qf[mf][kd] = *reinterpret_cast<const f16x8*>(
                Q + base + (size_t)(wq0 + mf * 16 + lr) * D_ + kd * 32 + lg * 8);

    f32x4 zacc[2][4] = {};
    float mrun[2][4], lsum[2][4];
#pragma unroll
    for (int mf = 0; mf < 2; ++mf)
#pragma unroll
        for (int r = 0; r < 4; ++r) { mrun[mf][r] = -3.0e38f; lsum[mf][r] = 0.f; }

    const float sc = 0.125f * 1.44269504f; // 1/sqrt(64) * log2(e)
    const int nt = ((wq0 + 31) >> 6) + 1;  // per-wave causal tile count

    for (int it = 0; it < nt; ++it) {
        const int t0 = it * 64;
        // ---- S = Q K^T
        f32x4 sf[2][4] = {};
#pragma unroll
        for (int kd = 0; kd < 2; ++kd)
#pragma unroll
            for (int n = 0; n < 4; ++n) {
                f16x8 kf = *reinterpret_cast<const f16x8*>(
                    Kg + base + (size_t)(t0 + n * 16 + lr) * D_ + kd * 32 + lg * 8);
#pragma unroll
                for (int mf = 0; mf < 2; ++mf)
                    sf[mf][n] = __builtin_amdgcn_mfma_f32_16x16x32_f16(qf[mf][kd], kf, sf[mf][n], 0, 0, 0);
            }
        // ---- scale (+ mask last tile of this wave)
        if (it == nt - 1) {
#pragma unroll
            for (int mf = 0; mf < 2; ++mf)
#pragma unroll
                for (int n = 0; n < 4; ++n)
#pragma unroll
                    for (int r = 0; r < 4; ++r) {
                        const bool masked = (t0 + n * 16 + lr) > (wq0 + mf * 16 + lg * 4 + r);
                        sf[mf][n][r] = masked ? -3.0e38f : sf[mf][n][r] * sc;
                    }
        } else {
#pragma unroll
            for (int mf = 0; mf < 2; ++mf)
#pragma unroll
                for (int n = 0; n < 4; ++n)
#pragma unroll
                    for (int r = 0; r < 4; ++r) sf[mf][n][r] *= sc;
        }
        // ---- online softmax (log2 domain); rows live at (mf, lg, r), reduce over n + lanes lr
#pragma unroll
        for (int mf = 0; mf < 2; ++mf)
#pragma unroll
            for (int r = 0; r < 4; ++r) {
                float v = fmaxf(fmaxf(sf[mf][0][r], sf[mf][1][r]), fmaxf(sf[mf][2][r], sf[mf][3][r]));
                v = fmaxf(v, __shfl_xor(v, 1));
                v = fmaxf(v, __shfl_xor(v, 2));
                v = fmaxf(v, __shfl_xor(v, 4));
                v = fmaxf(v, __shfl_xor(v, 8));
                const float mnew = fmaxf(mrun[mf][r], v);
                const float al = __builtin_amdgcn_exp2f(mrun[mf][r] - mnew);
                mrun[mf][r] = mnew;
                float s = 0.f;
#pragma unroll
                for (int n = 0; n < 4; ++n) {
                    const float p = __builtin_amdgcn_exp2f(sf[mf][n][r] - mnew);
                    sf[mf][n][r] = p;
                    s += p;
                }
                s += __shfl_xor(s, 1);
                s += __shfl_xor(s, 2);
                s += __shfl_xor(s, 4);
                s += __shfl_xor(s, 8);
                lsum[mf][r] = lsum[mf][r] * al + s;
#pragma unroll
                for (int n = 0; n < 4; ++n) zacc[mf][n][r] *= al;
            }
        // ---- P -> per-wave LDS (D-frag -> A-frag layout); wave-internal, no barrier
#pragma unroll
        for (int mf = 0; mf < 2; ++mf)
#pragma unroll
            for (int n = 0; n < 4; ++n)
#pragma unroll
                for (int r = 0; r < 4; ++r)
                    Pl[w][mf * 16 + lg * 4 + r][n * 16 + lr] = (f16)sf[mf][n][r];
        // ---- Z += P V
#pragma unroll
        for (int kt = 0; kt < 2; ++kt) {
            f16x8 pa[2];
#pragma unroll
            for (int mf = 0; mf < 2; ++mf)
                pa[mf] = *reinterpret_cast<const f16x8*>(&Pl[w][mf * 16 + lr][kt * 32 + lg * 8]);
#pragma unroll
            for (int n = 0; n < 4; ++n) {
                f16x8 vf = *reinterpret_cast<const f16x8*>(
                    Vt + vtbase + (size_t)(n * 16 + lr) * S_ + t0 + kt * 32 + lg * 8);
#pragma unroll
                for (int mf = 0; mf < 2; ++mf)
                    zacc[mf][n] = __builtin_amdgcn_mfma_f32_16x16x32_f16(pa[mf], vf, zacc[mf][n], 0, 0, 0);
            }
        }
    }
    // ---- epilogue
#pragma unroll
    for (int mf = 0; mf < 2; ++mf)
#pragma unroll
        for (int n = 0; n < 4; ++n)
#pragma unroll
            for (int r = 0; r < 4; ++r)
                Z[base + (size_t)(wq0 + mf * 16 + lg * 4 + r) * D_ + n * 16 + lr] =
                    (f16)(zacc[mf][n][r] / lsum[mf][r]);
}

// ---------------------------------------------------------------- launcher
extern "C" void kernel_launch(void* const* d_in, const int* in_sizes, int n_in,
                              void* d_out, int out_size, void* d_ws, size_t ws_size,
                              hipStream_t stream) {
    const float* data    = (const float*)d_in[0];
    const float* context = (const float*)d_in[1];
    const float* Wq = (const float*)d_in[2];
    const float* bq = (const float*)d_in[3];
    const float* Wk = (const float*)d_in[4];
    const float* bk = (const float*)d_in[5];
    const float* Wv = (const float*)d_in[6];
    const float* bv = (const float*)d_in[7];
    const float* Wo = (const float*)d_in[8];
    const float* bo = (const float*)d_in[9];

    const size_t MD = (size_t)M_ * D_;
    const size_t DD = (size_t)D_ * D_;
    f16* dataB = (f16*)d_ws;
    f16* ctxB  = dataB + MD;
    f16* WqT   = ctxB + MD;
    f16* WkT   = WqT + DD;
    f16* WvT   = WkT + DD;
    f16* WoT   = WvT + DD;
    f16* Qb    = WoT + DD;
    f16* Kb    = Qb + MD;
    f16* VtB   = Kb + MD;  // [B][H][HD][S]
    f16* Zb    = VtB + MD;

    const int n4 = (int)(MD / 4);
    cvt_kernel<<<n4 / 256, 256, 0, stream>>>(data, dataB, n4);
    cvt_kernel<<<n4 / 256, 256, 0, stream>>>(context, ctxB, n4);
    dim3 tb(32, 8), tg(32, 32);
    transpose_cvt_kernel<<<tg, tb, 0, stream>>>(Wq, WqT);
    transpose_cvt_kernel<<<tg, tb, 0, stream>>>(Wk, WkT);
    transpose_cvt_kernel<<<tg, tb, 0, stream>>>(Wv, WvT);
    transpose_cvt_kernel<<<tg, tb, 0, stream>>>(Wo, WoT);

    dim3 gg(D_ / 128, M_ / 128); // (8, 64)
    gemm_bt<0, f16><<<gg, 256, 0, stream>>>(dataB, WqT, bq, Qb);
    gemm_bt<0, f16><<<gg, 256, 0, stream>>>(ctxB,  WkT, bk, Kb);
    gemm_bt<2, f16><<<gg, 256, 0, stream>>>(ctxB,  WvT, bv, VtB);

    attn_kernel<<<dim3(S_ / 128, H_, B_), 256, 0, stream>>>(Qb, Kb, VtB, Zb);

    gemm_bt<1, float><<<gg, 256, 0, stream>>>(Zb, WoT, bo, (float*)d_out);
}

// Round 3
// 285.447 us; speedup vs baseline: 1.7281x; 1.3721x over previous
//
#include <hip/hip_runtime.h>

// Problem constants
#define B_  4
#define S_  2048
#define D_  1024
#define H_  16
#define HD_ 64
#define M_  (B_*S_)   // 8192 rows total

typedef _Float16 f16;
typedef f16  f16x8 __attribute__((ext_vector_type(8)));
typedef f16  f16x4 __attribute__((ext_vector_type(4)));
typedef float f32x4 __attribute__((ext_vector_type(4)));

// ---------------------------------------------------------------- converts
__global__ __launch_bounds__(256) void cvt_kernel(const float* __restrict__ in,
                                                  f16* __restrict__ out, int n4) {
    int i = blockIdx.x * 256 + threadIdx.x;
    if (i < n4) {
        f32x4 v = *reinterpret_cast<const f32x4*>(in + (size_t)i * 4);
        *reinterpret_cast<f16x4*>(out + (size_t)i * 4) = __builtin_convertvector(v, f16x4);
    }
}

// W[K=1024][N=1024] f32 -> WT[N][K] f16
__global__ __launch_bounds__(256) void transpose_cvt_kernel(const float* __restrict__ W,
                                                            f16* __restrict__ WT) {
    __shared__ float tile[32][33];
    const int n0 = blockIdx.x * 32, k0 = blockIdx.y * 32;
    const int tx = threadIdx.x, ty = threadIdx.y; // (32,8)
#pragma unroll
    for (int j = 0; j < 4; ++j)
        tile[ty + 8 * j][tx] = W[(size_t)(k0 + ty + 8 * j) * D_ + n0 + tx];
    __syncthreads();
#pragma unroll
    for (int j = 0; j < 4; ++j)
        WT[(size_t)(n0 + ty + 8 * j) * D_ + k0 + tx] = (f16)tile[tx][ty + 8 * j];
}

// ---------------------------------------------------------------- GEMM  C = A @ Bt^T + bias
// MODE 0: OutT=f16 row-major [M][D].  MODE 1: float row-major (final output).
// MODE 2: f16, output written transposed per-head: VT[B][H][HD][S] (for attention V).
template <int MODE, typename OutT>
__global__ __launch_bounds__(256) void gemm_bt(const f16* __restrict__ A,
                                               const f16* __restrict__ Bt,
                                               const float* __restrict__ bias,
                                               OutT* __restrict__ C) {
    constexpr int K = D_;
    __shared__ __align__(16) f16 Al[128][40];
    __shared__ __align__(16) f16 Bl[128][40];
    const int m0 = blockIdx.y * 128, n0 = blockIdx.x * 128;
    const int tid = threadIdx.x;
    const int w = tid >> 6, l = tid & 63, lr = l & 15, lg = l >> 4;
    const int wr = w >> 1, wc = w & 1;
    f32x4 acc[4][4] = {};
    for (int kk = 0; kk < K; kk += 32) {
        __syncthreads();
#pragma unroll
        for (int i = 0; i < 2; ++i) {
            int c = tid + i * 256;
            int row = c >> 2, off = (c & 3) * 8;
            *reinterpret_cast<f16x8*>(&Al[row][off]) =
                *reinterpret_cast<const f16x8*>(A + (size_t)(m0 + row) * K + kk + off);
            *reinterpret_cast<f16x8*>(&Bl[row][off]) =
                *reinterpret_cast<const f16x8*>(Bt + (size_t)(n0 + row) * K + kk + off);
        }
        __syncthreads();
        f16x8 a[4], b[4];
#pragma unroll
        for (int m = 0; m < 4; ++m)
            a[m] = *reinterpret_cast<const f16x8*>(&Al[wr * 64 + m * 16 + lr][lg * 8]);
#pragma unroll
        for (int n = 0; n < 4; ++n)
            b[n] = *reinterpret_cast<const f16x8*>(&Bl[wc * 64 + n * 16 + lr][lg * 8]);
#pragma unroll
        for (int m = 0; m < 4; ++m)
#pragma unroll
            for (int n = 0; n < 4; ++n)
                acc[m][n] = __builtin_amdgcn_mfma_f32_16x16x32_f16(a[m], b[n], acc[m][n], 0, 0, 0);
    }
#pragma unroll
    for (int n = 0; n < 4; ++n) {
        const int col = n0 + wc * 64 + n * 16 + lr;
        const float bv = bias[col];
#pragma unroll
        for (int m = 0; m < 4; ++m) {
            const int row = m0 + wr * 64 + m * 16 + lg * 4;
            if (MODE == 2) {
                const int bb = row >> 11, s0 = row & 2047;
                f16x4 v;
#pragma unroll
                for (int r = 0; r < 4; ++r) v[r] = (f16)(acc[m][n][r] + bv);
                *reinterpret_cast<f16x4*>((f16*)C + ((size_t)(bb * D_ + col)) * S_ + s0) = v;
            } else {
#pragma unroll
                for (int r = 0; r < 4; ++r)
                    C[(size_t)(row + r) * D_ + col] = (OutT)(acc[m][n][r] + bv);
            }
        }
    }
}

// ---------------------------------------------------------------- causal flash attention
// grid (H, B, S/128) — q-tile is SLOWEST dim so work is uncorrelated with XCD (id%8).
// 256 threads = 4 waves, NO barriers. Wave owns 32 q-rows (2 frags of 16). KV tile = 64.
// Swapped QK^T: mfma(K, Q) -> lane owns one q-row's scores in-register.
__global__ __launch_bounds__(256) void attn_kernel(const f16* __restrict__ Q,
                                                   const f16* __restrict__ Kg,
                                                   const f16* __restrict__ Vt,
                                                   f16* __restrict__ Z) {
    __shared__ __align__(16) f16 Pl[4][32][72]; // per-wave P (32q x 64k), padded
    const int h = blockIdx.x, b = blockIdx.y;
    const int qt = (int)gridDim.z - 1 - (int)blockIdx.z; // heavy tiles first
    const int q0 = qt * 128;
    const int tid = threadIdx.x, w = tid >> 6, l = tid & 63, lr = l & 15, lg = l >> 4;
    const size_t base   = ((size_t)b * S_) * D_ + h * HD_;
    const size_t vtbase = ((size_t)(b * D_ + h * HD_)) * S_;
    const int wq0 = q0 + w * 32;

    f16x8 qf[2][2]; // B-operand frags: col = q (lr), k = lg*8+e
#pragma unroll
    for (int mf = 0; mf < 2; ++mf)
#pragma unroll
        for (int kd = 0; kd < 2; ++kd)
            qf[mf][kd] = *reinterpret_cast<const f16x8*>(
                Q + base + (size_t)(wq0 + mf * 16 + lr) * D_ + kd * 32 + lg * 8);

    f32x4 zacc[2][4] = {};
    float mrun[2] = {-3.0e38f, -3.0e38f}, lsum[2] = {0.f, 0.f};

    const float sc = 0.125f * 1.44269504f; // 1/sqrt(64) * log2(e)
    const int nt = ((wq0 + 31) >> 6) + 1;  // per-wave causal tile count

    for (int it = 0; it < nt; ++it) {
        const int t0 = it * 64;
        // ---- S^T = K Q^T : D[row=key][col=q]; lane: q = lr, keys = n*16 + lg*4 + r
        f32x4 sf[2][4] = {};
#pragma unroll
        for (int kd = 0; kd < 2; ++kd)
#pragma unroll
            for (int n = 0; n < 4; ++n) {
                f16x8 kf = *reinterpret_cast<const f16x8*>(
                    Kg + base + (size_t)(t0 + n * 16 + lr) * D_ + kd * 32 + lg * 8);
#pragma unroll
                for (int mf = 0; mf < 2; ++mf)
                    sf[mf][n] = __builtin_amdgcn_mfma_f32_16x16x32_f16(kf, qf[mf][kd], sf[mf][n], 0, 0, 0);
            }
        // ---- scale (+ mask last tile of this wave)
        if (it == nt - 1) {
#pragma unroll
            for (int mf = 0; mf < 2; ++mf)
#pragma unroll
                for (int n = 0; n < 4; ++n)
#pragma unroll
                    for (int r = 0; r < 4; ++r) {
                        const bool masked = (t0 + n * 16 + lg * 4 + r) > (wq0 + mf * 16 + lr);
                        sf[mf][n][r] = masked ? -3.0e38f : sf[mf][n][r] * sc;
                    }
        } else {
#pragma unroll
            for (int mf = 0; mf < 2; ++mf)
#pragma unroll
                for (int n = 0; n < 4; ++n)
#pragma unroll
                    for (int r = 0; r < 4; ++r) sf[mf][n][r] *= sc;
        }
        // ---- online softmax: lane owns q = lr (per mf); 16 values in-register,
        //      cross-lane only over lg groups (xor 16, 32).
        float alpha[2];
#pragma unroll
        for (int mf = 0; mf < 2; ++mf) {
            f32x4 t4;
#pragma unroll
            for (int r = 0; r < 4; ++r)
                t4[r] = fmaxf(fmaxf(sf[mf][0][r], sf[mf][1][r]), fmaxf(sf[mf][2][r], sf[mf][3][r]));
            float vmax = fmaxf(fmaxf(t4[0], t4[1]), fmaxf(t4[2], t4[3]));
            vmax = fmaxf(vmax, __shfl_xor(vmax, 16));
            vmax = fmaxf(vmax, __shfl_xor(vmax, 32));
            const float mnew = fmaxf(mrun[mf], vmax);
            alpha[mf] = __builtin_amdgcn_exp2f(mrun[mf] - mnew);
            mrun[mf] = mnew;
            float s = 0.f;
#pragma unroll
            for (int n = 0; n < 4; ++n) {
                f32x4 p;
#pragma unroll
                for (int r = 0; r < 4; ++r) p[r] = __builtin_amdgcn_exp2f(sf[mf][n][r] - mnew);
                sf[mf][n] = p;
                s += (p[0] + p[1]) + (p[2] + p[3]);
            }
            s += __shfl_xor(s, 16);
            s += __shfl_xor(s, 32);
            lsum[mf] = lsum[mf] * alpha[mf] + s;
        }
        // ---- P -> per-wave LDS as packed f16x4 (r consecutive); wave-internal, no barrier
#pragma unroll
        for (int mf = 0; mf < 2; ++mf)
#pragma unroll
            for (int n = 0; n < 4; ++n) {
                f16x4 pv;
#pragma unroll
                for (int r = 0; r < 4; ++r) pv[r] = (f16)sf[mf][n][r];
                *reinterpret_cast<f16x4*>(&Pl[w][mf * 16 + lr][n * 16 + lg * 4]) = pv;
            }
        // ---- rescale zacc: need alpha for q = lg*4+r -> broadcast from lane (lg*4+r)
#pragma unroll
        for (int mf = 0; mf < 2; ++mf)
#pragma unroll
            for (int r = 0; r < 4; ++r) {
                const float ar = __shfl(alpha[mf], lg * 4 + r);
#pragma unroll
                for (int n = 0; n < 4; ++n) zacc[mf][n][r] *= ar;
            }
        // ---- Z += P V  (unchanged layout: A=P[q][t], B=V[t][d] from Vt[d][t])
#pragma unroll
        for (int kt = 0; kt < 2; ++kt) {
            f16x8 pa[2];
#pragma unroll
            for (int mf = 0; mf < 2; ++mf)
                pa[mf] = *reinterpret_cast<const f16x8*>(&Pl[w][mf * 16 + lr][kt * 32 + lg * 8]);
#pragma unroll
            for (int n = 0; n < 4; ++n) {
                f16x8 vf = *reinterpret_cast<const f16x8*>(
                    Vt + vtbase + (size_t)(n * 16 + lr) * S_ + t0 + kt * 32 + lg * 8);
#pragma unroll
                for (int mf = 0; mf < 2; ++mf)
                    zacc[mf][n] = __builtin_amdgcn_mfma_f32_16x16x32_f16(pa[mf], vf, zacc[mf][n], 0, 0, 0);
            }
        }
    }
    // ---- epilogue: divide by lsum (broadcast per row) and store
#pragma unroll
    for (int mf = 0; mf < 2; ++mf) {
        const float inv = 1.0f / lsum[mf];
#pragma unroll
        for (int r = 0; r < 4; ++r) {
            const float ir = __shfl(inv, lg * 4 + r);
#pragma unroll
            for (int n = 0; n < 4; ++n)
                Z[base + (size_t)(wq0 + mf * 16 + lg * 4 + r) * D_ + n * 16 + lr] =
                    (f16)(zacc[mf][n][r] * ir);
        }
    }
}

// ---------------------------------------------------------------- launcher
extern "C" void kernel_launch(void* const* d_in, const int* in_sizes, int n_in,
                              void* d_out, int out_size, void* d_ws, size_t ws_size,
                              hipStream_t stream) {
    const float* data    = (const float*)d_in[0];
    const float* context = (const float*)d_in[1];
    const float* Wq = (const float*)d_in[2];
    const float* bq = (const float*)d_in[3];
    const float* Wk = (const float*)d_in[4];
    const float* bk = (const float*)d_in[5];
    const float* Wv = (const float*)d_in[6];
    const float* bv = (const float*)d_in[7];
    const float* Wo = (const float*)d_in[8];
    const float* bo = (const float*)d_in[9];

    const size_t MD = (size_t)M_ * D_;
    const size_t DD = (size_t)D_ * D_;
    f16* dataB = (f16*)d_ws;
    f16* ctxB  = dataB + MD;
    f16* WqT   = ctxB + MD;
    f16* WkT   = WqT + DD;
    f16* WvT   = WkT + DD;
    f16* WoT   = WvT + DD;
    f16* Qb    = WoT + DD;
    f16* Kb    = Qb + MD;
    f16* VtB   = Kb + MD;  // [B][H][HD][S]
    f16* Zb    = VtB + MD;

    const int n4 = (int)(MD / 4);
    cvt_kernel<<<n4 / 256, 256, 0, stream>>>(data, dataB, n4);
    cvt_kernel<<<n4 / 256, 256, 0, stream>>>(context, ctxB, n4);
    dim3 tb(32, 8), tg(32, 32);
    transpose_cvt_kernel<<<tg, tb, 0, stream>>>(Wq, WqT);
    transpose_cvt_kernel<<<tg, tb, 0, stream>>>(Wk, WkT);
    transpose_cvt_kernel<<<tg, tb, 0, stream>>>(Wv, WvT);
    transpose_cvt_kernel<<<tg, tb, 0, stream>>>(Wo, WoT);

    dim3 gg(D_ / 128, M_ / 128); // (8, 64)
    gemm_bt<0, f16><<<gg, 256, 0, stream>>>(dataB, WqT, bq, Qb);
    gemm_bt<0, f16><<<gg, 256, 0, stream>>>(ctxB,  WkT, bk, Kb);
    gemm_bt<2, f16><<<gg, 256, 0, stream>>>(ctxB,  WvT, bv, VtB);

    attn_kernel<<<dim3(H_, B_, S_ / 128), 256, 0, stream>>>(Qb, Kb, VtB, Zb);

    gemm_bt<1, float><<<gg, 256, 0, stream>>>(Zb, WoT, bo, (float*)d_out);
}